// Round 1
// baseline (209.608 us; speedup 1.0000x reference)
//
#include <hip/hip_runtime.h>

// Multiclass hinge loss (sum over batch):
//   loss = sum_i [ sum_j max(out[i,j] - out[i,y_i] + 1, 0) ] - B
// (the j==y_i term is exactly 1.0, so excluding it == subtracting 1 per row)

__global__ __launch_bounds__(256) void
msrp_hinge_kernel(const float* __restrict__ outs,
                  const int* __restrict__ labels,
                  float* __restrict__ result,
                  int B, int C) {
    const int gtid   = blockIdx.x * blockDim.x + threadIdx.x;
    const int wave   = gtid >> 6;                       // global wave id
    const int lane   = threadIdx.x & 63;
    const int nwaves = (gridDim.x * blockDim.x) >> 6;

    const int f4_per_lane = C >> 8;                     // C/4 float4 / 64 lanes

    float acc = 0.0f;
    int rows = 0;

    for (int row = wave; row < B; row += nwaves) {
        const float* rp = outs + (size_t)row * C;
        const int lab = labels[row];                    // wave-uniform -> s_load
        const float bias = 1.0f - rp[lab];              // wave-uniform broadcast

        const float4* rp4 = (const float4*)rp;
        float s = 0.0f;
        #pragma unroll
        for (int k = 0; k < 8; ++k) {                   // C==2048 -> 8 iters
            if (k < f4_per_lane) {
                float4 v = rp4[lane + (k << 6)];
                s += fmaxf(v.x + bias, 0.0f);
                s += fmaxf(v.y + bias, 0.0f);
                s += fmaxf(v.z + bias, 0.0f);
                s += fmaxf(v.w + bias, 0.0f);
            }
        }
        acc += s;
        ++rows;                                         // ground term: +1.0/row
    }

    // wave reduction (64 lanes)
    #pragma unroll
    for (int off = 32; off >= 1; off >>= 1)
        acc += __shfl_xor(acc, off, 64);

    // remove the ground-truth terms (1.0 per processed row)
    acc -= (float)rows;

    // block reduction: 4 waves -> 1 atomic
    __shared__ float wsum[4];
    if (lane == 0) wsum[threadIdx.x >> 6] = acc;
    __syncthreads();
    if (threadIdx.x == 0) {
        float t = wsum[0] + wsum[1] + wsum[2] + wsum[3];
        atomicAdd(result, t);
    }
}

extern "C" void kernel_launch(void* const* d_in, const int* in_sizes, int n_in,
                              void* d_out, int out_size, void* d_ws, size_t ws_size,
                              hipStream_t stream) {
    const float* outs  = (const float*)d_in[0];
    const int* labels  = (const int*)d_in[1];
    float* result      = (float*)d_out;

    const int B = in_sizes[1];              // 16384
    const int C = in_sizes[0] / B;          // 2048

    // d_out is re-poisoned to 0xAA before every timed launch — zero it first.
    hipMemsetAsync(result, 0, sizeof(float), stream);

    const int block = 256;
    const int grid  = 2048;                 // 8192 waves, grid-stride over rows
    msrp_hinge_kernel<<<grid, block, 0, stream>>>(outs, labels, result, B, C);
}

// Round 2
// 190.738 us; speedup vs baseline: 1.0989x; 1.0989x over previous
//
#include <hip/hip_runtime.h>

// Multiclass hinge loss (sum over batch):
//   loss = sum_i [ sum_j max(out[i,j] - out[i,y_i] + 1, 0) ] - B
// (the j==y_i term is exactly 1.0, so excluding it == subtracting 1 per row)
//
// Two-kernel scheme, no atomics, no d_out/d_ws zeroing needed:
//   kernel1: per-block partial sums -> d_ws[block]   (plain stores)
//   kernel2: 1 block sums the 2048 partials -> d_out (plain store)

#define GRID1 2048
#define BLOCK1 256

__global__ __launch_bounds__(BLOCK1) void
hinge_partial_kernel(const float* __restrict__ outs,
                     const int* __restrict__ labels,
                     float* __restrict__ part,
                     int B, int C) {
    const int gtid   = blockIdx.x * blockDim.x + threadIdx.x;
    const int wave   = gtid >> 6;                       // global wave id
    const int lane   = threadIdx.x & 63;
    const int nwaves = (gridDim.x * blockDim.x) >> 6;

    const int f4_per_lane = C >> 8;                     // (C/4) / 64 lanes

    float acc = 0.0f;
    int rows = 0;

    for (int row = wave; row < B; row += nwaves) {
        const float* rp = outs + (size_t)row * C;
        const int lab = labels[row];
        const float bias = 1.0f - rp[lab];              // wave-uniform value

        const float4* rp4 = (const float4*)rp;
        float s = 0.0f;
        #pragma unroll 8
        for (int k = 0; k < f4_per_lane; ++k) {         // C==2048 -> 8 iters
            float4 v = rp4[lane + (k << 6)];
            s += fmaxf(v.x + bias, 0.0f);
            s += fmaxf(v.y + bias, 0.0f);
            s += fmaxf(v.z + bias, 0.0f);
            s += fmaxf(v.w + bias, 0.0f);
        }
        acc += s;
        ++rows;                                         // ground term: +1.0/row
    }

    // wave reduction (64 lanes)
    #pragma unroll
    for (int off = 32; off >= 1; off >>= 1)
        acc += __shfl_xor(acc, off, 64);

    acc -= (float)rows;                                 // remove ground terms

    // block reduction: 4 waves -> one plain store (no atomic, no init needed)
    __shared__ float wsum[4];
    if (lane == 0) wsum[threadIdx.x >> 6] = acc;
    __syncthreads();
    if (threadIdx.x == 0)
        part[blockIdx.x] = wsum[0] + wsum[1] + wsum[2] + wsum[3];
}

__global__ __launch_bounds__(256) void
hinge_final_kernel(const float* __restrict__ part,
                   float* __restrict__ result, int n) {
    float acc = 0.0f;
    for (int i = threadIdx.x; i < n; i += 256)          // 2048/256 = 8 each
        acc += part[i];

    #pragma unroll
    for (int off = 32; off >= 1; off >>= 1)
        acc += __shfl_xor(acc, off, 64);

    __shared__ float wsum[4];
    const int lane = threadIdx.x & 63;
    if (lane == 0) wsum[threadIdx.x >> 6] = acc;
    __syncthreads();
    if (threadIdx.x == 0)
        *result = wsum[0] + wsum[1] + wsum[2] + wsum[3];
}

extern "C" void kernel_launch(void* const* d_in, const int* in_sizes, int n_in,
                              void* d_out, int out_size, void* d_ws, size_t ws_size,
                              hipStream_t stream) {
    const float* outs  = (const float*)d_in[0];
    const int* labels  = (const int*)d_in[1];
    float* result      = (float*)d_out;
    float* part        = (float*)d_ws;                  // 2048 floats of scratch

    const int B = in_sizes[1];              // 16384
    const int C = in_sizes[0] / B;          // 2048

    hinge_partial_kernel<<<GRID1, BLOCK1, 0, stream>>>(outs, labels, part, B, C);
    hinge_final_kernel<<<1, 256, 0, stream>>>(part, result, GRID1);
}

// Round 6
// 182.588 us; speedup vs baseline: 1.1480x; 1.0446x over previous
//
#include <hip/hip_runtime.h>

// Multiclass hinge loss (sum over batch):
//   loss = sum_i [ sum_j max(out[i,j] - out[i,y_i] + 1, 0) ] - B
// (the j==y_i term is exactly 1.0, so excluding it == subtracting 1 per row;
//  the entire correction "- B" is applied ONCE in the final kernel — partial
//  kernels sum raw margins over ALL j, so no per-wave/per-lane bookkeeping.)
//
// kernel1: per-block partial sums (all-j margins) -> d_ws[block]  (plain stores)
// kernel2: 1 block sums partials, subtracts B -> d_out            (plain store)

#define GRID1 2048
#define BLOCK1 256

typedef float f32x4 __attribute__((ext_vector_type(4)));

__global__ __launch_bounds__(BLOCK1) void
hinge_partial_kernel(const float* __restrict__ outs,
                     const int* __restrict__ labels,
                     float* __restrict__ part,
                     int B, int C) {
    const int gtid   = blockIdx.x * blockDim.x + threadIdx.x;
    const int wave   = gtid >> 6;
    const int lane   = threadIdx.x & 63;
    const int nwaves = (gridDim.x * blockDim.x) >> 6;

    const int f4_per_lane = C >> 8;                     // (C/4) / 64 lanes

    float acc = 0.0f;                                   // raw margin sum (all j)

    if (B == 2 * nwaves && (C & 255) == 0) {
        // ---- fast path: rows {wave, wave+nwaves}, streams interleaved ----
        const int r0 = wave, r1 = wave + nwaves;
        const int lab0 = labels[r0], lab1 = labels[r1];
        const float* rp0 = outs + (size_t)r0 * C;
        const float* rp1 = outs + (size_t)r1 * C;
        const float bias0 = 1.0f - rp0[lab0];           // wave-uniform
        const float bias1 = 1.0f - rp1[lab1];

        const f32x4* p0 = (const f32x4*)rp0;
        const f32x4* p1 = (const f32x4*)rp1;
        float s0 = 0.0f, s1 = 0.0f;
        #pragma unroll 8
        for (int k = 0; k < f4_per_lane; ++k) {         // 8 iters at C=2048
            f32x4 v0 = __builtin_nontemporal_load(&p0[lane + (k << 6)]);
            f32x4 v1 = __builtin_nontemporal_load(&p1[lane + (k << 6)]);
            s0 += fmaxf(v0.x + bias0, 0.0f) + fmaxf(v0.y + bias0, 0.0f)
                + fmaxf(v0.z + bias0, 0.0f) + fmaxf(v0.w + bias0, 0.0f);
            s1 += fmaxf(v1.x + bias1, 0.0f) + fmaxf(v1.y + bias1, 0.0f)
                + fmaxf(v1.z + bias1, 0.0f) + fmaxf(v1.w + bias1, 0.0f);
        }
        acc = s0 + s1;                                  // NO subtraction here
    } else {
        // ---- generic fallback (also raw all-j margins) ----
        for (int row = wave; row < B; row += nwaves) {
            const float* rp = outs + (size_t)row * C;
            const int lab = labels[row];
            const float bias = 1.0f - rp[lab];
            float s = 0.0f;
            for (int j = lane; j < C; j += 64)
                s += fmaxf(rp[j] + bias, 0.0f);
            acc += s;
        }
    }

    // wave reduction (64 lanes)
    #pragma unroll
    for (int off = 32; off >= 1; off >>= 1)
        acc += __shfl_xor(acc, off, 64);

    // block reduction: 4 waves -> one plain store
    __shared__ float wsum[4];
    if (lane == 0) wsum[threadIdx.x >> 6] = acc;
    __syncthreads();
    if (threadIdx.x == 0)
        part[blockIdx.x] = wsum[0] + wsum[1] + wsum[2] + wsum[3];
}

__global__ __launch_bounds__(256) void
hinge_final_kernel(const float* __restrict__ part,
                   float* __restrict__ result, int n, int B) {
    float acc = 0.0f;
    for (int i = threadIdx.x; i < n; i += 256)
        acc += part[i];

    #pragma unroll
    for (int off = 32; off >= 1; off >>= 1)
        acc += __shfl_xor(acc, off, 64);

    __shared__ float wsum[4];
    const int lane = threadIdx.x & 63;
    if (lane == 0) wsum[threadIdx.x >> 6] = acc;
    __syncthreads();
    if (threadIdx.x == 0)
        *result = (wsum[0] + wsum[1] + wsum[2] + wsum[3]) - (float)B;
}

extern "C" void kernel_launch(void* const* d_in, const int* in_sizes, int n_in,
                              void* d_out, int out_size, void* d_ws, size_t ws_size,
                              hipStream_t stream) {
    const float* outs  = (const float*)d_in[0];
    const int* labels  = (const int*)d_in[1];
    float* result      = (float*)d_out;
    float* part        = (float*)d_ws;                  // 2048 floats of scratch

    const int B = in_sizes[1];              // 16384
    const int C = in_sizes[0] / B;          // 2048

    hinge_partial_kernel<<<GRID1, BLOCK1, 0, stream>>>(outs, labels, part, B, C);
    hinge_final_kernel<<<1, 256, 0, stream>>>(part, result, GRID1, B);
}